// Round 5
// baseline (399.301 us; speedup 1.0000x reference)
//
#include <hip/hip_runtime.h>

typedef unsigned short u16;
typedef unsigned int u32;
typedef __attribute__((ext_vector_type(8))) short short8;
typedef __attribute__((ext_vector_type(4))) float floatx4;

#define EPSV 1e-5f
#define WS_ELEMS 167936

__device__ __forceinline__ float b2f(u16 u){
  union { float f; u32 i; } c; c.i = ((u32)u) << 16; return c.f;
}
__device__ __forceinline__ u16 f2b(float f){   // RNE
  union { float f; u32 i; } c; c.f = f;
  u32 r = c.i + 0x7FFFu + ((c.i >> 16) & 1u);
  return (u16)(r >> 16);
}
__device__ __forceinline__ u16 f2bc(float f){  // cheap round (intermediates)
  union { float f; u32 i; } c; c.f = f;
  return (u16)((c.i + 0x8000u) >> 16);
}
__device__ __forceinline__ float ldf(const void* p, int i, bool isf){
  return isf ? ((const float*)p)[i] : b2f(((const u16*)p)[i]);
}
__device__ __forceinline__ bool detect_f32(const void* g_emb){
  return *(const u32*)g_emb == 0x3F800000u;
}
__device__ __forceinline__ void dma16(const u16* g, u16* l){
  __builtin_amdgcn_global_load_lds((const __attribute__((address_space(1))) u32*)(g),
                                   (__attribute__((address_space(3))) u32*)(l), 16, 0, 0);
}
__device__ __forceinline__ void dma_slab(const u16* g, u16* dst, int wave, int lane){
  #pragma unroll
  for (int i = 0; i < 4; i++){
    int c = (wave << 2) + i;
    dma16(g + (c << 9) + (lane << 3), dst + (c << 9));
  }
}
// bank swizzle: XOR low2 of the group m-part with its high2 (involution)
__device__ __forceinline__ int swz(int lane){
  return (lane & ~3) | ((lane ^ (lane >> 2)) & 3);
}
// element offset in a frag-chunked tile: chunk, quad(k-octet), m(row 0..15), j
__device__ __forceinline__ int fragoff(int chunk, int quad, int m, int j){
  return (chunk << 9) + ((((quad << 4) | (m & 12) | ((m ^ (m >> 2)) & 3))) << 3) + j;
}
__device__ __forceinline__ short8 frg(const u16* p, int chunk, int swl){
  return *(const short8*)(p + (chunk << 9) + (swl << 3));
}

// ---------------- prep: weights -> swizzled frag-stream order in ws ----------------
// [0,4096) emb (2 halves x 4 chunks, K=32 pad)  [4096,20480) enc (2 x 16 chunks)
// [20480,..) 18 slabs of 8192: (d*2+h)*3 + {0:Wv,1:Wk,2:Wq}
__global__ void prep_kernel(const void* W_emb, const void* W_enc,
                            const void* Wq, const void* Wk, const void* Wv,
                            const void* g_emb, u16* ws){
  bool isf = detect_f32(g_emb);
  int e = blockIdx.x * 256 + threadIdx.x;
  if (e >= WS_ELEMS) return;
  float v;
  if (e < 4096){
    int half = e >> 11, r = e & 2047;
    int q = (r >> 3) & 63, j = r & 7;
    int ql = (q & ~3) | ((q ^ (q >> 2)) & 3);
    int col = half*64 + ((r >> 9) << 4) + (ql & 15);
    int k = (ql >> 4)*8 + j;
    v = (k < 16) ? ldf(W_emb, k*128 + col, isf) : 0.0f;
  } else if (e < 20480){
    int i = e - 4096;
    int half = i >> 13, r = i & 8191;
    int chunk = r >> 9, q = (r >> 3) & 63, j = r & 7;
    int ql = (q & ~3) | ((q ^ (q >> 2)) & 3);
    int ks = chunk >> 2, nt = chunk & 3;
    int col = half*64 + nt*16 + (ql & 15);
    int k = ks*32 + (ql >> 4)*8 + j;
    v = ldf(W_enc, k*128 + col, isf);
  } else {
    int i = e - 20480;
    int slab = i >> 13, r = i & 8191;
    int dh = slab / 3, which = slab - dh*3;
    int d = dh >> 1, h = dh & 1;
    int chunk = r >> 9, q = (r >> 3) & 63, j = r & 7;
    int ql = (q & ~3) | ((q ^ (q >> 2)) & 3);
    int ks = chunk >> 2, nt = chunk & 3;
    int col = h*64 + nt*16 + (ql & 15);
    int k = ks*32 + (ql >> 4)*8 + j;
    const void* W = (which == 0) ? Wv : (which == 1) ? Wk : Wq;
    v = ldf(W, d*16384 + k*128 + col, isf);
  }
  ws[e] = f2b(v);
}

#define MFMA(a,b,c) __builtin_amdgcn_mfma_f32_16x16x32_bf16((a),(b),(c),0,0,0)

// 1x4 row-sliced gemm (enc): D rows = wave's 16, 64 cols
__device__ __forceinline__ void gemmW(const u16* sh, const u16* slab, int wave, int swl, floatx4* acc){
  #pragma unroll
  for (int ks = 0; ks < 4; ks++){
    short8 a = frg(sh, ks*4 + wave, swl);
    #pragma unroll
    for (int nt = 0; nt < 4; nt++)
      acc[nt] = MFMA(a, frg(slab, ks*4 + nt, swl), acc[nt]);
  }
}
// 2x2 tiled gemm: wave covers rows [ra*16, +32), cols [cb*16, +32)
__device__ __forceinline__ void gemm2x2(const u16* A, const u16* B, int ra, int cb_, int swl, floatx4* acc){
  #pragma unroll
  for (int ks = 0; ks < 4; ks++){
    short8 a0 = frg(A, ks*4 + ra,     swl);
    short8 a1 = frg(A, ks*4 + ra + 1, swl);
    short8 b0 = frg(B, ks*4 + cb_,     swl);
    short8 b1 = frg(B, ks*4 + cb_ + 1, swl);
    acc[0] = MFMA(a0, b0, acc[0]);
    acc[1] = MFMA(a0, b1, acc[1]);
    acc[2] = MFMA(a1, b0, acc[2]);
    acc[3] = MFMA(a1, b1, acc[3]);
  }
}

__device__ __forceinline__ void red_sum2(float* s1, float* s2){
  #pragma unroll
  for (int m = 1; m < 16; m <<= 1){
    #pragma unroll
    for (int r = 0; r < 4; r++){
      s1[r] += __shfl_xor(s1[r], m, 64);
      s2[r] += __shfl_xor(s2[r], m, 64);
    }
  }
}

// proj write, bias per-col (K, Q)
__device__ __forceinline__ void pwrite_col(floatx4* a4, u16* dst, const u16* bias,
    int wr, int wc, int lq, int lc){
  #pragma unroll
  for (int tc = 0; tc < 2; tc++){
    float bb = b2f(bias[wc*32 + tc*16 + lc]);
    #pragma unroll
    for (int tr = 0; tr < 2; tr++){
      #pragma unroll
      for (int r = 0; r < 4; r++)
        dst[fragoff(wc*4 + wr*2 + tr, tc*2 + (lc >> 3), lq*4 + r, lc & 7)]
          = f2bc(a4[tr*2+tc][r] + bb);
    }
  }
}
// proj write, bias per-row (V^T)
__device__ __forceinline__ void pwrite_row(floatx4* a4, u16* dst, const u16* bias,
    int wr, int wc, int lq, int lc){
  #pragma unroll
  for (int tr = 0; tr < 2; tr++){
    float bb[4];
    #pragma unroll
    for (int r = 0; r < 4; r++) bb[r] = b2f(bias[wr*32 + tr*16 + lq*4 + r]);
    #pragma unroll
    for (int tc = 0; tc < 2; tc++)
      #pragma unroll
      for (int r = 0; r < 4; r++)
        dst[fragoff(wc*4 + wr*2 + tr, tc*2 + (lc >> 3), lq*4 + r, lc & 7)]
          = f2bc(a4[tr*2+tc][r] + bb[r]);
  }
}

// LN epilogue, MLP flavor (global bias/g/beta, relu after); fills xres (f32)
__device__ __forceinline__ void ln_mlp(floatx4* acc, const void* bias, const void* g,
    const void* bet, bool isf, float xres[8][4], int wave, int lq, int lc, u16* sh){
  float s1[4] = {0,0,0,0}, s2[4] = {0,0,0,0};
  #pragma unroll
  for (int nt = 0; nt < 8; nt++){
    float bb = ldf(bias, nt*16 + lc, isf);
    #pragma unroll
    for (int r = 0; r < 4; r++){
      float v = acc[nt][r] + bb;
      xres[nt][r] = v; s1[r] += v; s2[r] += v*v;
    }
  }
  red_sum2(s1, s2);
  float mean[4], rstd[4];
  #pragma unroll
  for (int r = 0; r < 4; r++){
    mean[r] = s1[r] * (1.0f/128.0f);
    rstd[r] = rsqrtf(s2[r]*(1.0f/128.0f) - mean[r]*mean[r] + EPSV);
  }
  #pragma unroll
  for (int nt = 0; nt < 8; nt++){
    float gg = ldf(g, nt*16 + lc, isf), bb = ldf(bet, nt*16 + lc, isf);
    #pragma unroll
    for (int r = 0; r < 4; r++){
      float y = fmaxf((xres[nt][r] - mean[r]) * rstd[r] * gg + bb, 0.0f);
      xres[nt][r] = y;
      sh[fragoff((nt >> 1)*4 + wave, ((nt & 1) << 1) + (lc >> 3), lq*4 + r, lc & 7)] = f2bc(y);
    }
  }
}

// LN epilogue, attention: x = relu(ctx) + xres(regs); consts in LDS
__device__ __forceinline__ void ln_attn(floatx4* ctx, float xres[8][4], const u16* cb,
                                        int wave, int lq, int lc, u16* sh){
  float s1[4] = {0,0,0,0}, s2[4] = {0,0,0,0};
  #pragma unroll
  for (int nt = 0; nt < 8; nt++)
    #pragma unroll
    for (int r = 0; r < 4; r++){
      float v = fmaxf(ctx[nt][r], 0.0f) + xres[nt][r];
      xres[nt][r] = v; s1[r] += v; s2[r] += v*v;
    }
  red_sum2(s1, s2);
  float mean[4], rstd[4];
  #pragma unroll
  for (int r = 0; r < 4; r++){
    mean[r] = s1[r] * (1.0f/128.0f);
    rstd[r] = rsqrtf(s2[r]*(1.0f/128.0f) - mean[r]*mean[r] + EPSV);
  }
  #pragma unroll
  for (int nt = 0; nt < 8; nt++){
    float gg = b2f(cb[384 + nt*16 + lc]), bb = b2f(cb[512 + nt*16 + lc]);
    #pragma unroll
    for (int r = 0; r < 4; r++){
      float y = (xres[nt][r] - mean[r]) * rstd[r] * gg + bb;
      xres[nt][r] = y;
      sh[fragoff((nt >> 1)*4 + wave, ((nt & 1) << 1) + (lc >> 3), lq*4 + r, lc & 7)] = f2bc(y);
    }
  }
}

__global__ __launch_bounds__(256, 3)
void fused_kernel(const void* feat, const void* masks,
                  const void* b_emb, const void* g_emb, const void* be_emb,
                  const void* b_enc, const void* g_enc, const void* be_enc,
                  const void* bq, const void* bk, const void* bv,
                  const void* ln_g, const void* ln_b,
                  const u16* ws, void* out){
  __shared__ __align__(16) u16 s_h[8192];   // hidden, frag-order       16384B
  __shared__ __align__(16) u16 s_w[8192];   // slab / Q[0,8) P[8,16)    16384B
  __shared__ __align__(16) u16 s_k[4096];   // K frag-order              8192B
  __shared__ __align__(16) u16 s_v[4096];   // V^T frag-order            8192B
  __shared__ u16 s_c[1920];                 // per-d consts              3840B
  __shared__ float s_valid[64];             //                            256B

  int tid = threadIdx.x;
  int wave = tid >> 6, lane = tid & 63, lq = lane >> 4, lc = lane & 15;
  int wr = wave >> 1, wc = wave & 1;
  int swl = swz(lane);
  int n = blockIdx.x;
  bool isf = detect_f32(g_emb);
  const floatx4 z4 = {0.0f, 0.0f, 0.0f, 0.0f};

  // emb slab DMA (8 chunks, 2 per wave)
  dma16(ws + ((wave*2 + 0) << 9) + (lane << 3), s_w + ((wave*2 + 0) << 9));
  dma16(ws + ((wave*2 + 1) << 9) + (lane << 3), s_w + ((wave*2 + 1) << 9));

  // feat [64][16] -> s_h frag-order chunk t>>4 (ks=0; zero-pad quads 2,3)
  if (!isf){
    const u16* fp = (const u16*)feat + n*1024;
    if (tid < 128){
      int t = tid >> 1, half = tid & 1;
      uint4 v = *(const uint4*)(fp + t*16 + half*8);
      *(uint4*)(s_h + fragoff(t >> 4, half, t & 15, 0)) = v;
    } else {
      int t = (tid - 128) >> 1, half = 2 + ((tid - 128) & 1);
      uint4 z; z.x = z.y = z.z = z.w = 0;
      *(uint4*)(s_h + fragoff(t >> 4, half, t & 15, 0)) = z;
    }
  } else {
    for (int i = tid; i < 2048; i += 256){
      int t = i >> 5, k = i & 31;
      float v = (k < 16) ? ((const float*)feat)[n*1024 + t*16 + k] : 0.0f;
      s_h[fragoff(t >> 4, k >> 3, t & 15, k & 7)] = f2b(v);
    }
  }
  for (int i = tid; i < 1920; i += 256){
    int blk = i >> 7, off = i & 127;
    int d = blk / 5, wh = blk - d*5;
    const void* src = (wh == 0) ? bq : (wh == 1) ? bk : (wh == 2) ? bv : (wh == 3) ? ln_g : ln_b;
    s_c[i] = isf ? f2b(((const float*)src)[d*128 + off]) : ((const u16*)src)[d*128 + off];
  }
  if (tid < 64) s_valid[tid] = (ldf(masks, n*64 + tid, isf) == 0.0f) ? 1.0f : 0.0f;
  __syncthreads();                                        // B0

  float xres[8][4];
  floatx4 acc[8];
  #pragma unroll
  for (int i = 0; i < 8; i++) acc[i] = z4;
  // ---- emb (K=32) ----
  {
    short8 a = frg(s_h, wave, swl);
    #pragma unroll
    for (int nt = 0; nt < 4; nt++){
      acc[nt]     = MFMA(a, frg(s_w, nt,     swl), acc[nt]);
      acc[4 + nt] = MFMA(a, frg(s_w, 4 + nt, swl), acc[4 + nt]);
    }
  }
  __syncthreads();                                        // B1
  dma_slab(ws + 4096, s_w, wave, lane);                   // ENC_A
  ln_mlp(acc, b_emb, g_emb, be_emb, isf, xres, wave, lq, lc, s_h);
  __syncthreads();                                        // B2

  #pragma unroll
  for (int i = 0; i < 8; i++) acc[i] = z4;
  gemmW(s_h, s_w, wave, swl, acc);
  __syncthreads();                                        // B3
  dma_slab(ws + 12288, s_w, wave, lane);                  // ENC_B
  __syncthreads();                                        // B4
  gemmW(s_h, s_w, wave, swl, acc + 4);
  __syncthreads();                                        // B5
  dma_slab(ws + 20480, s_w, wave, lane);                  // Wv d0 h0
  ln_mlp(acc, b_enc, g_enc, be_enc, isf, xres, wave, lq, lc, s_h);
  __syncthreads();                                        // B6

  int sb = 20480;
  for (int d = 0; d < 3; d++){
    const u16* cb = s_c + d*640;
    floatx4 ctx[8];
    #pragma unroll
    for (int i = 0; i < 8; i++) ctx[i] = z4;

    for (int h = 0; h < 2; h++){
      floatx4 pa[4];
      // ---- V^T = Wv^T @ h^T (2x2: A=slab rows hd, B=s_h cols t) ----
      #pragma unroll
      for (int i = 0; i < 4; i++) pa[i] = z4;
      gemm2x2(s_w, s_h, wr*2, wc*2, swl, pa);
      __syncthreads();                                    // H1: Wv free
      dma_slab(ws + sb + 8192, s_w, wave, lane);          // Wk
      pwrite_row(pa, s_v, cb + 256 + h*64, wr, wc, lq, lc);
      __syncthreads();                                    // H2: Wk ready, s_v ready
      // ---- K (2x2: A=s_h, B=slab) ----
      #pragma unroll
      for (int i = 0; i < 4; i++) pa[i] = z4;
      gemm2x2(s_h, s_w, wr*2, wc*2, swl, pa);
      __syncthreads();                                    // H3: Wk free
      dma_slab(ws + sb + 16384, s_w, wave, lane);         // Wq
      pwrite_col(pa, s_k, cb + 128 + h*64, wr, wc, lq, lc);
      __syncthreads();                                    // H4: Wq ready, s_k ready
      // ---- Q (2x2) ----
      #pragma unroll
      for (int i = 0; i < 4; i++) pa[i] = z4;
      gemm2x2(s_h, s_w, wr*2, wc*2, swl, pa);
      __syncthreads();                                    // H5: Wq free -> overlay
      pwrite_col(pa, s_w, cb + h*64, wr, wc, lq, lc);     // Q -> s_w chunks [0,8)
      __syncthreads();                                    // H5b: Q visible
      // ---- scores = Q K^T / 8 + mask (rows wave-sliced) ----
      #pragma unroll
      for (int i = 0; i < 4; i++) pa[i] = z4;
      #pragma unroll
      for (int ks = 0; ks < 2; ks++){
        short8 a = frg(s_w, ks*4 + wave, swl);
        #pragma unroll
        for (int nt = 0; nt < 4; nt++)
          pa[nt] = MFMA(a, frg(s_k, ks*4 + nt, swl), pa[nt]);
      }
      float rv[4], cv[4];
      #pragma unroll
      for (int r = 0; r < 4; r++) rv[r] = s_valid[wave*16 + (lq << 2) + r];
      #pragma unroll
      for (int nt = 0; nt < 4; nt++) cv[nt] = s_valid[nt*16 + lc];

      float p[4][4];
      #pragma unroll
      for (int nt = 0; nt < 4; nt++)
        #pragma unroll
        for (int r = 0; r < 4; r++)
          p[nt][r] = pa[nt][r]*0.125f - 10000.0f*(1.0f - rv[r]*cv[nt]);

      float mx[4];
      #pragma unroll
      for (int r = 0; r < 4; r++)
        mx[r] = fmaxf(fmaxf(p[0][r], p[1][r]), fmaxf(p[2][r], p[3][r]));
      #pragma unroll
      for (int m = 1; m < 16; m <<= 1)
        #pragma unroll
        for (int r = 0; r < 4; r++) mx[r] = fmaxf(mx[r], __shfl_xor(mx[r], m, 64));

      float sm[4] = {0,0,0,0};
      #pragma unroll
      for (int nt = 0; nt < 4; nt++)
        #pragma unroll
        for (int r = 0; r < 4; r++){ p[nt][r] = __expf(p[nt][r] - mx[r]); sm[r] += p[nt][r]; }
      #pragma unroll
      for (int m = 1; m < 16; m <<= 1)
        #pragma unroll
        for (int r = 0; r < 4; r++) sm[r] += __shfl_xor(sm[r], m, 64);

      float inv[4];
      #pragma unroll
      for (int r = 0; r < 4; r++) inv[r] = 1.0f / sm[r];

      // P -> s_w chunks [8,16), wave-private pair
      #pragma unroll
      for (int nt = 0; nt < 4; nt++)
        #pragma unroll
        for (int r = 0; r < 4; r++)
          s_w[fragoff(8 + 2*wave + (nt >> 1), ((nt & 1) << 1) + (lc >> 3), lq*4 + r, lc & 7)]
            = f2bc(p[nt][r] * inv[r]);
      // ---- ctx += P @ V ----
      #pragma unroll
      for (int ks = 0; ks < 2; ks++){
        short8 a = frg(s_w, 8 + 2*wave + ks, swl);
        #pragma unroll
        for (int nt = 0; nt < 4; nt++)
          ctx[h*4 + nt] = MFMA(a, frg(s_v, ks*4 + nt, swl), ctx[h*4 + nt]);
      }
      __syncthreads();                                    // H6
      sb += 24576;
      if (!(d == 2 && h == 1)) dma_slab(ws + sb, s_w, wave, lane);  // next Wv
      if (h == 1) ln_attn(ctx, xres, cb, wave, lq, lc, s_h);
      __syncthreads();                                    // H7
    }
  }

  // ---- max over T ----
  if (tid < 128){
    int col = tid;
    float mxv = -1e30f;
    #pragma unroll 4
    for (int t = 0; t < 64; t++)
      mxv = fmaxf(mxv, b2f(s_h[fragoff(((col >> 5) << 2) + (t >> 4), (col >> 3) & 3, t & 15, col & 7)]));
    if (isf) ((float*)out)[n*128 + col] = mxv;
    else     ((u16*)out)[n*128 + col] = f2b(mxv);
  }
}

extern "C" void kernel_launch(void* const* d_in, const int* in_sizes, int n_in,
                              void* d_out, int out_size, void* d_ws, size_t ws_size,
                              hipStream_t stream){
  const void* feat   = d_in[0];
  const void* masks  = d_in[1];
  const void* W_emb  = d_in[2];
  const void* b_emb  = d_in[3];
  const void* g_emb  = d_in[4];
  const void* be_emb = d_in[5];
  const void* W_enc  = d_in[6];
  const void* b_enc  = d_in[7];
  const void* g_enc  = d_in[8];
  const void* be_enc = d_in[9];
  const void* Wq     = d_in[10];
  const void* bq     = d_in[11];
  const void* Wk     = d_in[12];
  const void* bk     = d_in[13];
  const void* Wv     = d_in[14];
  const void* bv     = d_in[15];
  const void* ln_g   = d_in[16];
  const void* ln_b   = d_in[17];
  u16* ws = (u16*)d_ws;

  hipLaunchKernelGGL(prep_kernel, dim3((WS_ELEMS + 255)/256), dim3(256), 0, stream,
                     W_emb, W_enc, Wq, Wk, Wv, g_emb, ws);
  hipLaunchKernelGGL(fused_kernel, dim3(4096), dim3(256), 0, stream,
                     feat, masks, b_emb, g_emb, be_emb, b_enc, g_enc, be_enc,
                     bq, bk, bv, ln_g, ln_b, ws, d_out);
}

// Round 8
// 383.103 us; speedup vs baseline: 1.0423x; 1.0423x over previous
//
#include <hip/hip_runtime.h>

typedef unsigned short u16;
typedef unsigned int u32;
typedef __attribute__((ext_vector_type(8))) short short8;
typedef __attribute__((ext_vector_type(4))) float floatx4;

#define EPSV 1e-5f
#define WS_ELEMS 167936

__device__ __forceinline__ float b2f(u16 u){
  union { float f; u32 i; } c; c.i = ((u32)u) << 16; return c.f;
}
__device__ __forceinline__ u16 f2b(float f){   // RNE (prep + final out)
  union { float f; u32 i; } c; c.f = f;
  u32 r = c.i + 0x7FFFu + ((c.i >> 16) & 1u);
  return (u16)(r >> 16);
}
__device__ __forceinline__ u16 f2bc(float f){  // cheap round (intermediates)
  union { float f; u32 i; } c; c.f = f;
  return (u16)((c.i + 0x8000u) >> 16);
}
__device__ __forceinline__ float ldf(const void* p, int i, bool isf){
  return isf ? ((const float*)p)[i] : b2f(((const u16*)p)[i]);
}
__device__ __forceinline__ bool detect_f32(const void* g_emb){
  return *(const u32*)g_emb == 0x3F800000u;
}
__device__ __forceinline__ void dma16(const u16* g, u16* l){
  __builtin_amdgcn_global_load_lds((const __attribute__((address_space(1))) u32*)(g),
                                   (__attribute__((address_space(3))) u32*)(l), 16, 0, 0);
}
// stage a full 16-chunk (8192-elem) slab, 4 chunks per wave
__device__ __forceinline__ void dma_slab(const u16* g, u16* dst, int wave, int lane){
  #pragma unroll
  for (int i = 0; i < 4; i++){
    int c = (wave << 2) + i;
    dma16(g + (c << 9) + (lane << 3), dst + (c << 9));
  }
}

// ---------------- prep: weights -> frag-stream order in ws ----------------
// ws (bf16): [0,4096) emb (2 halves x 4 chunks, K=32, k>=16 zero)
//            [4096,20480) enc (2 halves x 16 chunks, K=128)
//            [20480,...) 18 slabs of 8192: s=(d*2+h)*3+{0:Wv,1:Wk,2:Wq}
__global__ void prep_kernel(const void* W_emb, const void* W_enc,
                            const void* Wq, const void* Wk, const void* Wv,
                            const void* g_emb, u16* ws){
  bool isf = detect_f32(g_emb);
  int e = blockIdx.x * 256 + threadIdx.x;
  if (e >= WS_ELEMS) return;
  float v;
  if (e < 4096){
    int half = e >> 11, r = e & 2047;
    int nt = r >> 9, q = (r >> 3) & 63, j = r & 7;
    int col = half*64 + nt*16 + (q & 15);
    int k = (q >> 4)*8 + j;
    v = (k < 16) ? ldf(W_emb, k*128 + col, isf) : 0.0f;
  } else if (e < 20480){
    int i = e - 4096;
    int half = i >> 13, r = i & 8191;
    int chunk = r >> 9, q = (r >> 3) & 63, j = r & 7;
    int ks = chunk >> 2, nt = chunk & 3;
    int col = half*64 + nt*16 + (q & 15);
    int k = ks*32 + (q >> 4)*8 + j;
    v = ldf(W_enc, k*128 + col, isf);
  } else {
    int i = e - 20480;
    int slab = i >> 13, r = i & 8191;
    int dh = slab / 3, which = slab - dh*3;
    int d = dh >> 1, h = dh & 1;
    int chunk = r >> 9, q = (r >> 3) & 63, j = r & 7;
    int ks = chunk >> 2, nt = chunk & 3;
    int col = h*64 + nt*16 + (q & 15);
    int k = ks*32 + (q >> 4)*8 + j;
    const void* W = (which == 0) ? Wv : (which == 1) ? Wk : Wq;
    v = ldf(W, d*16384 + k*128 + col, isf);
  }
  ws[e] = f2b(v);
}

// ---------------- frag helpers ----------------
__device__ __forceinline__ short8 frg(const u16* p, int chunk, int lane){
  return *(const short8*)(p + (chunk << 9) + (lane << 3));
}
// epilogue write offset into a frag-order target (r adds +8 each)
__device__ __forceinline__ int wfoff(int wave, int nt, int lq, int lc){
  return ((((nt >> 1) << 2) + wave) << 9)
       + ((((((nt << 1) + (lc >> 3)) & 3) << 4) + (lq << 2)) << 3) + (lc & 7);
}
// wave-private Q/P region offset inside s_w
__device__ __forceinline__ int qfoff(int wave, int nt, int lq, int lc){
  return (wave << 10) + ((nt >> 1) << 9)
       + ((((((nt << 1) + (lc >> 3)) & 3) << 4) + (lq << 2)) << 3) + (lc & 7);
}

// D rows = wave's 16 t-rows, 64 cols: A = s_h, B = slab (K=128)
__device__ __forceinline__ void gemmW(const u16* sh, const u16* slab, int wave, int lane, floatx4* acc){
  #pragma unroll
  for (int ks = 0; ks < 4; ks++){
    short8 a = frg(sh, ks*4 + wave, lane);
    #pragma unroll
    for (int nt = 0; nt < 4; nt++)
      acc[nt] = __builtin_amdgcn_mfma_f32_16x16x32_bf16(a, frg(slab, ks*4 + nt, lane), acc[nt], 0, 0, 0);
  }
}
// swapped: D rows = wave's 16 hd-rows, cols = t (V^T): A = slab, B = s_h
__device__ __forceinline__ void gemmWT(const u16* sh, const u16* slab, int wave, int lane, floatx4* acc){
  #pragma unroll
  for (int ks = 0; ks < 4; ks++){
    short8 a = frg(slab, ks*4 + wave, lane);
    #pragma unroll
    for (int nt = 0; nt < 4; nt++)
      acc[nt] = __builtin_amdgcn_mfma_f32_16x16x32_bf16(a, frg(sh, ks*4 + nt, lane), acc[nt], 0, 0, 0);
  }
}
// K=64 gemm: A = wave-private region in s_w, B = 8-chunk frag target
__device__ __forceinline__ void gemm64(const u16* areg, const u16* b, int wave, int lane, floatx4* acc){
  #pragma unroll
  for (int ks = 0; ks < 2; ks++){
    short8 a = *(const short8*)(areg + (wave << 10) + (ks << 9) + (lane << 3));
    #pragma unroll
    for (int nt = 0; nt < 4; nt++)
      acc[nt] = __builtin_amdgcn_mfma_f32_16x16x32_bf16(a, frg(b, ks*4 + nt, lane), acc[nt], 0, 0, 0);
  }
}

__device__ __forceinline__ void red_sum2(float* s1, float* s2){
  #pragma unroll
  for (int m = 1; m < 16; m <<= 1){
    #pragma unroll
    for (int r = 0; r < 4; r++){
      s1[r] += __shfl_xor(s1[r], m, 64);
      s2[r] += __shfl_xor(s2[r], m, 64);
    }
  }
}

// LN epilogue, MLP flavor (bias/g/beta from global, relu after); fills xres (f32 resid)
__device__ __forceinline__ void ln_mlp(floatx4* acc, const void* bias, const void* g,
    const void* bet, bool isf, float xres[8][4], int wave, int lq, int lc, u16* sh){
  float x[8][4], s1[4] = {0,0,0,0}, s2[4] = {0,0,0,0};
  #pragma unroll
  for (int nt = 0; nt < 8; nt++){
    float bb = ldf(bias, nt*16 + lc, isf);
    #pragma unroll
    for (int r = 0; r < 4; r++){
      float v = acc[nt][r] + bb;
      x[nt][r] = v; s1[r] += v; s2[r] += v*v;
    }
  }
  red_sum2(s1, s2);
  float mean[4], rstd[4];
  #pragma unroll
  for (int r = 0; r < 4; r++){
    mean[r] = s1[r] * (1.0f/128.0f);
    rstd[r] = rsqrtf(s2[r]*(1.0f/128.0f) - mean[r]*mean[r] + EPSV);
  }
  #pragma unroll
  for (int nt = 0; nt < 8; nt++){
    float gg = ldf(g, nt*16 + lc, isf), bb = ldf(bet, nt*16 + lc, isf);
    int o = wfoff(wave, nt, lq, lc);
    #pragma unroll
    for (int r = 0; r < 4; r++){
      float y = fmaxf((x[nt][r] - mean[r]) * rstd[r] * gg + bb, 0.0f);
      xres[nt][r] = y;
      sh[o + 8*r] = f2bc(y);
    }
  }
}

// LN epilogue, attention flavor: x = relu(ctx) + xres (f32 registers); consts from LDS
__device__ __forceinline__ void ln_attn(floatx4* ctx, float xres[8][4], const u16* cb,
                                        int wave, int lq, int lc, u16* sh){
  float x[8][4], s1[4] = {0,0,0,0}, s2[4] = {0,0,0,0};
  #pragma unroll
  for (int nt = 0; nt < 8; nt++){
    #pragma unroll
    for (int r = 0; r < 4; r++){
      float v = fmaxf(ctx[nt][r], 0.0f) + xres[nt][r];
      x[nt][r] = v; s1[r] += v; s2[r] += v*v;
    }
  }
  red_sum2(s1, s2);
  float mean[4], rstd[4];
  #pragma unroll
  for (int r = 0; r < 4; r++){
    mean[r] = s1[r] * (1.0f/128.0f);
    rstd[r] = rsqrtf(s2[r]*(1.0f/128.0f) - mean[r]*mean[r] + EPSV);
  }
  #pragma unroll
  for (int nt = 0; nt < 8; nt++){
    float gg = b2f(cb[384 + nt*16 + lc]), bb = b2f(cb[512 + nt*16 + lc]);
    int o = wfoff(wave, nt, lq, lc);
    #pragma unroll
    for (int r = 0; r < 4; r++){
      float y = (x[nt][r] - mean[r]) * rstd[r] * gg + bb;
      xres[nt][r] = y;
      sh[o + 8*r] = f2bc(y);
    }
  }
}

__global__ __launch_bounds__(256, 3)
void fused_kernel(const void* feat, const void* masks,
                  const void* b_emb, const void* g_emb, const void* be_emb,
                  const void* b_enc, const void* g_enc, const void* be_enc,
                  const void* bq, const void* bk, const void* bv,
                  const void* ln_g, const void* ln_b,
                  const u16* ws, void* out){
  __shared__ __align__(16) u16 s_h[8192];   // hidden, frag-order (16 chunks)  16384B
  __shared__ __align__(16) u16 s_w[8192];   // weight slab / Q,P overlay       16384B
  __shared__ __align__(16) u16 s_k[4096];   // K frag-order (8 chunks)          8192B
  __shared__ __align__(16) u16 s_v[4096];   // V^T frag-order (8 chunks)        8192B
  __shared__ u16 s_c[1920];                 // per-d consts (bq,bk,bv,lng,lnb)  3840B
  __shared__ float s_valid[64];             //                                   256B

  int tid = threadIdx.x;
  int wave = tid >> 6, lane = tid & 63, lq = lane >> 4, lc = lane & 15;
  int n = blockIdx.x;
  bool isf = detect_f32(g_emb);
  const floatx4 z4 = {0.0f, 0.0f, 0.0f, 0.0f};

  // emb slab DMA (8 chunks, 2 per wave)
  dma16(ws + ((wave*2 + 0) << 9) + (lane << 3), s_w + ((wave*2 + 0) << 9));
  dma16(ws + ((wave*2 + 1) << 9) + (lane << 3), s_w + ((wave*2 + 1) << 9));

  // feat [64][16] -> s_h frag-order (ks=0; zero-pad k=16..31)
  if (!isf){
    const u16* fp = (const u16*)feat + n*1024;
    if (tid < 128){
      int t = tid >> 1, half = tid & 1;
      uint4 v = *(const uint4*)(fp + t*16 + half*8);
      *(uint4*)(s_h + ((t >> 4) << 9) + (((half << 4) + (t & 15)) << 3)) = v;
    } else {
      int t = (tid - 128) >> 1, half = 2 + ((tid - 128) & 1);
      uint4 z; z.x = 0; z.y = 0; z.z = 0; z.w = 0;
      *(uint4*)(s_h + ((t >> 4) << 9) + (((half << 4) + (t & 15)) << 3)) = z;
    }
  } else {
    for (int i = tid; i < 2048; i += 256){
      int t = i >> 5, k = i & 31;
      float v = (k < 16) ? ((const float*)feat)[n*1024 + t*16 + k] : 0.0f;
      s_h[((t >> 4) << 9) + ((((k >> 3) << 4) + (t & 15)) << 3) + (k & 7)] = f2b(v);
    }
  }
  // consts -> s_c (15 blocks of 128: d=blk/5, which)
  for (int i = tid; i < 1920; i += 256){
    int blk = i >> 7, off = i & 127;
    int d = blk / 5, wh = blk - d*5;
    const void* src = (wh == 0) ? bq : (wh == 1) ? bk : (wh == 2) ? bv : (wh == 3) ? ln_g : ln_b;
    s_c[i] = isf ? f2b(((const float*)src)[d*128 + off]) : ((const u16*)src)[d*128 + off];
  }
  if (tid < 64) s_valid[tid] = (ldf(masks, n*64 + tid, isf) == 0.0f) ? 1.0f : 0.0f;
  __syncthreads();                                        // B0

  float xres[8][4];
  floatx4 acc[8];
  #pragma unroll
  for (int i = 0; i < 8; i++) acc[i] = z4;
  // ---- emb (K=32, one A-frag reused for both halves) ----
  {
    short8 a = frg(s_h, wave, lane);
    #pragma unroll
    for (int nt = 0; nt < 4; nt++){
      acc[nt]     = __builtin_amdgcn_mfma_f32_16x16x32_bf16(a, frg(s_w, nt,     lane), acc[nt],     0,0,0);
      acc[4 + nt] = __builtin_amdgcn_mfma_f32_16x16x32_bf16(a, frg(s_w, 4 + nt, lane), acc[4 + nt], 0,0,0);
    }
  }
  __syncthreads();                                        // B1: emb slab free
  dma_slab(ws + 4096, s_w, wave, lane);                   // ENC_A
  ln_mlp(acc, b_emb, g_emb, be_emb, isf, xres, wave, lq, lc, s_h);
  __syncthreads();                                        // B2

  #pragma unroll
  for (int i = 0; i < 8; i++) acc[i] = z4;
  gemmW(s_h, s_w, wave, lane, acc);
  __syncthreads();                                        // B3
  dma_slab(ws + 12288, s_w, wave, lane);                  // ENC_B
  __syncthreads();                                        // B4
  gemmW(s_h, s_w, wave, lane, acc + 4);
  __syncthreads();                                        // B5
  dma_slab(ws + 20480, s_w, wave, lane);                  // Wv d0 h0
  ln_mlp(acc, b_enc, g_enc, be_enc, isf, xres, wave, lq, lc, s_h);
  __syncthreads();                                        // B6

  int sb = 20480;
  for (int d = 0; d < 3; d++){
    const u16* cb = s_c + d*640;
    floatx4 ctx[8];
    #pragma unroll
    for (int i = 0; i < 8; i++) ctx[i] = z4;

    for (int h = 0; h < 2; h++){
      floatx4 pa[4];
      // ---- V^T (A=Wv slab, B=s_h) ----
      #pragma unroll
      for (int i = 0; i < 4; i++) pa[i] = z4;
      gemmWT(s_h, s_w, wave, lane, pa);
      __syncthreads();                                    // H1: Wv free
      dma_slab(ws + sb + 8192, s_w, wave, lane);          // Wk
      {
        float bb4[4];
        #pragma unroll
        for (int r = 0; r < 4; r++) bb4[r] = b2f(cb[256 + h*64 + wave*16 + (lq << 2) + r]);
        #pragma unroll
        for (int nt = 0; nt < 4; nt++){
          int o = wfoff(wave, nt, lq, lc);
          #pragma unroll
          for (int r = 0; r < 4; r++) s_v[o + 8*r] = f2bc(pa[nt][r] + bb4[r]);
        }
      }
      __syncthreads();                                    // H2: Wk ready
      // ---- K ----
      #pragma unroll
      for (int i = 0; i < 4; i++) pa[i] = z4;
      gemmW(s_h, s_w, wave, lane, pa);
      __syncthreads();                                    // H3: Wk free
      dma_slab(ws + sb + 16384, s_w, wave, lane);         // Wq
      {
        #pragma unroll
        for (int nt = 0; nt < 4; nt++){
          float bb = b2f(cb[128 + h*64 + nt*16 + lc]);
          int o = wfoff(wave, nt, lq, lc);
          #pragma unroll
          for (int r = 0; r < 4; r++) s_k[o + 8*r] = f2bc(pa[nt][r] + bb);
        }
      }
      __syncthreads();                                    // H4: Wq ready
      // ---- Q ----
      #pragma unroll
      for (int i = 0; i < 4; i++) pa[i] = z4;
      gemmW(s_h, s_w, wave, lane, pa);
      __syncthreads();                                    // H5: Wq free -> overlay safe
      {
        #pragma unroll
        for (int nt = 0; nt < 4; nt++){
          float bb = b2f(cb[h*64 + nt*16 + lc]);
          int o = qfoff(wave, nt, lq, lc);
          #pragma unroll
          for (int r = 0; r < 4; r++) s_w[o + 8*r] = f2bc(pa[nt][r] + bb);
        }
      }
      // ---- scores (wave-private rows; same-wave DS ordering) ----
      #pragma unroll
      for (int i = 0; i < 4; i++) pa[i] = z4;
      gemm64(s_w, s_k, wave, lane, pa);

      float rv[4], cv[4];
      #pragma unroll
      for (int r = 0; r < 4; r++) rv[r] = s_valid[wave*16 + (lq << 2) + r];
      #pragma unroll
      for (int nt = 0; nt < 4; nt++) cv[nt] = s_valid[nt*16 + lc];

      float p[4][4];
      #pragma unroll
      for (int nt = 0; nt < 4; nt++)
        #pragma unroll
        for (int r = 0; r < 4; r++)
          p[nt][r] = pa[nt][r]*0.125f - 10000.0f*(1.0f - rv[r]*cv[nt]);

      float mx[4];
      #pragma unroll
      for (int r = 0; r < 4; r++)
        mx[r] = fmaxf(fmaxf(p[0][r], p[1][r]), fmaxf(p[2][r], p[3][r]));
      #pragma unroll
      for (int m = 1; m < 16; m <<= 1)
        #pragma unroll
        for (int r = 0; r < 4; r++) mx[r] = fmaxf(mx[r], __shfl_xor(mx[r], m, 64));

      float sm[4] = {0,0,0,0};
      #pragma unroll
      for (int nt = 0; nt < 4; nt++)
        #pragma unroll
        for (int r = 0; r < 4; r++){ p[nt][r] = __expf(p[nt][r] - mx[r]); sm[r] += p[nt][r]; }
      #pragma unroll
      for (int m = 1; m < 16; m <<= 1)
        #pragma unroll
        for (int r = 0; r < 4; r++) sm[r] += __shfl_xor(sm[r], m, 64);

      float inv[4];
      #pragma unroll
      for (int r = 0; r < 4; r++) inv[r] = 1.0f / sm[r];

      // P over Q (wave-private region)
      #pragma unroll
      for (int nt = 0; nt < 4; nt++){
        int o = qfoff(wave, nt, lq, lc);
        #pragma unroll
        for (int r = 0; r < 4; r++) s_w[o + 8*r] = f2bc(p[nt][r] * inv[r]);
      }
      // ---- ctx += P @ V ----
      gemm64(s_w, s_v, wave, lane, ctx + h*4);
      __syncthreads();                                    // H6: overlay/s_k/s_v free
      sb += 24576;
      if (!(d == 2 && h == 1)) dma_slab(ws + sb, s_w, wave, lane);  // next Wv
      if (h == 1) ln_attn(ctx, xres, cb, wave, lq, lc, s_h);
      __syncthreads();                                    // H7
    }
  }

  // ---- max over T ----
  if (tid < 128){
    int col = tid;
    float mxv = -1e30f;
    #pragma unroll 4
    for (int t = 0; t < 64; t++)
      mxv = fmaxf(mxv, b2f(s_h[((((col >> 5) << 2) + (t >> 4)) << 9)
                               + (((((col >> 3) & 3) << 4) + (t & 15)) << 3) + (col & 7)]));
    if (isf) ((float*)out)[n*128 + col] = mxv;
    else     ((u16*)out)[n*128 + col] = f2b(mxv);
  }
}

extern "C" void kernel_launch(void* const* d_in, const int* in_sizes, int n_in,
                              void* d_out, int out_size, void* d_ws, size_t ws_size,
                              hipStream_t stream){
  const void* feat   = d_in[0];
  const void* masks  = d_in[1];
  const void* W_emb  = d_in[2];
  const void* b_emb  = d_in[3];
  const void* g_emb  = d_in[4];
  const void* be_emb = d_in[5];
  const void* W_enc  = d_in[6];
  const void* b_enc  = d_in[7];
  const void* g_enc  = d_in[8];
  const void* be_enc = d_in[9];
  const void* Wq     = d_in[10];
  const void* bq     = d_in[11];
  const void* Wk     = d_in[12];
  const void* bk     = d_in[13];
  const void* Wv     = d_in[14];
  const void* bv     = d_in[15];
  const void* ln_g   = d_in[16];
  const void* ln_b   = d_in[17];
  u16* ws = (u16*)d_ws;

  hipLaunchKernelGGL(prep_kernel, dim3((WS_ELEMS + 255)/256), dim3(256), 0, stream,
                     W_emb, W_enc, Wq, Wk, Wv, g_emb, ws);
  hipLaunchKernelGGL(fused_kernel, dim3(4096), dim3(256), 0, stream,
                     feat, masks, b_emb, g_emb, be_emb, b_enc, g_enc, be_enc,
                     bq, bk, bv, ln_g, ln_b, ws, d_out);
}